// Round 6
// baseline (472.324 us; speedup 1.0000x reference)
//
#include <hip/hip_runtime.h>
#include <hip/hip_bf16.h>

// out[b,s,o] = sum_i x[b,s,i] * w[o,i]  -- NT GEMM M=8192, N=4096, K=4096
// w dequantized from 4-bit groups (256 vals/group, 16 groups per output row).

#define M_DIM 8192
#define N_DIM 4096
#define K_DIM 4096

typedef __bf16 bf16x8 __attribute__((ext_vector_type(8)));
typedef float f32x16 __attribute__((ext_vector_type(16)));
typedef unsigned short us8 __attribute__((ext_vector_type(8)));

__device__ __forceinline__ unsigned short f2bf_rne(float f) {
    unsigned int u = __builtin_bit_cast(unsigned int, f);
    u += 0x7FFFu + ((u >> 16) & 1u);
    return (unsigned short)(u >> 16);
}

// ---- fused prepass (unchanged) ---------------------------------------------
__global__ void prep_kernel(const float* __restrict__ x,
                            const int* __restrict__ packed,
                            const float* __restrict__ params,
                            ushort* __restrict__ a,
                            ushort* __restrict__ w) {
    int b = blockIdx.x;
    if (b < 16384) {
        int j = b * 256 + threadIdx.x;        // ushort8 index
        float4 v0 = ((const float4*)x)[2 * j];
        float4 v1 = ((const float4*)x)[2 * j + 1];
        us8 o;
        o[0] = f2bf_rne(v0.x); o[1] = f2bf_rne(v0.y);
        o[2] = f2bf_rne(v0.z); o[3] = f2bf_rne(v0.w);
        o[4] = f2bf_rne(v1.x); o[5] = f2bf_rne(v1.y);
        o[6] = f2bf_rne(v1.z); o[7] = f2bf_rne(v1.w);
        ((us8*)a)[j] = o;
    } else {
        int j = (b - 16384) * 256 + threadIdx.x;   // int4 index
        int4 v = ((const int4*)packed)[j];
        int g = j >> 5;                            // 4 ints same group
        float s = params[2 * g], z = params[2 * g + 1];
        unsigned int o0, o1, o2, o3;
        o0 = (unsigned int)f2bf_rne((float)(v.x & 15) * s + z)
           | ((unsigned int)f2bf_rne((float)((v.x >> 4) & 15) * s + z) << 16);
        o1 = (unsigned int)f2bf_rne((float)(v.y & 15) * s + z)
           | ((unsigned int)f2bf_rne((float)((v.y >> 4) & 15) * s + z) << 16);
        o2 = (unsigned int)f2bf_rne((float)(v.z & 15) * s + z)
           | ((unsigned int)f2bf_rne((float)((v.z >> 4) & 15) * s + z) << 16);
        o3 = (unsigned int)f2bf_rne((float)(v.w & 15) * s + z)
           | ((unsigned int)f2bf_rne((float)((v.w >> 4) & 15) * s + z) << 16);
        ((uint4*)w)[j] = make_uint4(o0, o1, o2, o3);
    }
}

// ---- main GEMM: 256x256, BK=64, r2 schedule, 32x32x16 MFMA -----------------
// Round-4 post-mortem: schedule reshuffles inside the 16x16x32 floor all land
// at ~58% MfmaUtil; VALUBusy/MfmaUtil = 0.34 constant (VALU = MFMA issue
// shadow, no real VALU). Round-5: lower the MFMA floor itself: 32x32x16
// (2382-2495 TF ubench) vs 16x16x32 (2075 TF): 256 MFMA x 8.07cyc = 2066
// cyc/tile/CU vs 2483 (-17%), 4x fewer issue slots. Staging, swizzle, vmcnt
// ledger, 2 barriers/tile identical to the proven r2 skeleton; phases now =
// k-steps (ks=0..3, K=16 each).
//
// Fragment layouts (32x32x16 bf16):
//   A/B input: row(col) = lane&31, k = (lane>>5)*8 + r  (K-doubled pattern,
//     same family as the working 16x16x32 kernel's (lane>>4)*8+r)
//   C/D (m74/m101-verified): col = lane&31,
//     row = (reg&3) + 8*(reg>>2) + 4*(lane>>5), reg in [0,16)
// LDS chunk swizzle: chunk c of row r holds global chunk c^(r&7); read chunk
// for k-step ks = (ks*2 + (lane>>5)) ^ (lane&7); per-8-lane group covers all
// 8 chunks -> full 32-bank coverage, conflict-free (same argument as r2).
//
// Per tile t (buf = parity of t, compile-time):
//   [entering: A(ks0) in afA, B(ks0) in bf0 -- read under prev MFMA(ks3)]
//   ph0: read B(ks1..3) [6], A(ks1)->afB [4]; stageA(t+1,h0); MFMA(ks0: afA,bf0)
//   ph1: read A(ks2)->afA [4]; stageA(t+1,h1); MFMA(ks1: afB,bfk[0]);
//        lgkmcnt(4)  <- pending = A(ks2) only; all B reads older -> retired
//        MID BARRIER (frees B-slot(t))
//   ph2: read A(ks3)->afB [4]; stageB(t+2,h0); MFMA(ks2: afA,bfk[1])
//   ph3: stageB(t+2,h1); vmcnt(4)+lgkmcnt(0); TILE BARRIER;
//        read bf0'(t+1), A'(ks0)->afA [6]; MFMA(ks3: afB,bfk[2])
// vmcnt ledger: at drain, outstanding = B(t+1):4 + A(t+1):4 + B(t+2):4 = 12
// -> vmcnt(4) retires B(t+1),A(t+1), leaves B(t+2) in flight (never 0).
__global__ __launch_bounds__(512, 2) void gemm_bt(const ushort* __restrict__ A,
                                                  const ushort* __restrict__ B,
                                                  float* __restrict__ C) {
    __shared__ ushort lds[65536];   // 128 KiB: A slots [0,32768), B [32768,65536)

    const int tid  = threadIdx.x;
    const int w    = tid >> 6;           // wave 0..7
    const int lane = tid & 63;
    const int r32  = lane & 31;
    const int hi   = lane >> 5;          // 0..1
    const int wm   = w >> 2;             // wave M index 0..1 (128 rows each)
    const int wn   = w & 3;              // wave N index 0..3 (64 cols each)

    // XCD-bijective swizzle (r2-proven): 64 contiguous per XCD, B-panel-major.
    const int bid = blockIdx.x;
    const int sid = (bid & 7) * 64 + (bid >> 3);
    const int by  = sid & 31;            // M tile 0..31
    const int bx  = sid >> 5;            // N tile 0..15
    const int m0  = by * 256;
    const int n0  = bx * 256;

    // staging source: thread t covers half-row (t>>3), pre-swizzled chunk
    const int srow = tid >> 3;                       // 0..63
    const int scol = ((tid & 7) ^ (srow & 7)) * 8;
    const ushort* aS = A + (size_t)(m0 + srow) * K_DIM + scol;
    const ushort* bS = B + (size_t)(n0 + srow) * K_DIM + scol;

    f32x16 acc[4][2] = {};               // [mi][nj], 128 regs
    bf16x8 afA[4], afB[4];               // A frag sets (4 mi), ks ping-pong
    bf16x8 bf0a[2], bf0b[2];             // B ks0, tile-parity ping-pong
    bf16x8 bfk[3][2];                    // B ks1..3 (literal-indexed only)

    auto stageA = [&](int t, int h) {
        const int kc   = (t < 64 ? t : 63) * 64;
        const int slot = ((t & 1) * 2 + h) * 8192;
#pragma unroll
        for (int l = 0; l < 2; ++l)
            __builtin_amdgcn_global_load_lds(
                (const __attribute__((address_space(1))) void*)(aS + (size_t)(h * 128 + l * 64) * K_DIM + kc),
                (__attribute__((address_space(3))) void*)(lds + slot + (l * 512 + w * 64) * 8),
                16, 0, 0);
    };
    auto stageB = [&](int t, int h) {
        const int kc   = (t < 64 ? t : 63) * 64;
        const int slot = 32768 + ((t & 1) * 2 + h) * 8192;
#pragma unroll
        for (int l = 0; l < 2; ++l)
            __builtin_amdgcn_global_load_lds(
                (const __attribute__((address_space(1))) void*)(bS + (size_t)(h * 128 + l * 64) * K_DIM + kc),
                (__attribute__((address_space(3))) void*)(lds + slot + (l * 512 + w * 64) * 8),
                16, 0, 0);
    };

    // per-lane base pointers, one per k-step; reads = base + imm only
    const int aBase = wm * 8192;                   // wave's A half-slot
    const int bBase = 32768 + (wn >> 1) * 8192;    // wave's B half-slot
    const int bR0   = (wn & 1) * 64;
    const int swz   = lane & 7;
    const ushort* pA[4];
    const ushort* pB[4];
#pragma unroll
    for (int ks = 0; ks < 4; ++ks) {
        const int c = ((ks * 2 + hi) ^ swz) * 8;   // swizzled chunk offset
        pA[ks] = lds + aBase + r32 * 64 + c;
        pB[ks] = lds + bBase + (bR0 + r32) * 64 + c;
    }

#define MFMA_KS(AF, B0, B1)                                                    \
    do {                                                                       \
        __builtin_amdgcn_s_setprio(1);                                         \
        _Pragma("unroll")                                                      \
        for (int mi = 0; mi < 4; ++mi) {                                       \
            acc[mi][0] = __builtin_amdgcn_mfma_f32_32x32x16_bf16(              \
                AF[mi], B0, acc[mi][0], 0, 0, 0);                              \
            acc[mi][1] = __builtin_amdgcn_mfma_f32_32x32x16_bf16(              \
                AF[mi], B1, acc[mi][1], 0, 0, 0);                              \
        }                                                                      \
        __builtin_amdgcn_s_setprio(0);                                         \
    } while (0)

// A frags for k-step KS from buffer BUF (both compile-time): 4 x ds_read_b128
#define READ_A(DST, BUF, KS)                                                   \
    do {                                                                       \
        _Pragma("unroll")                                                      \
        for (int mi = 0; mi < 4; ++mi)                                         \
            DST[mi] = *(const bf16x8*)(pA[KS] + (BUF) + mi * 2048);            \
    } while (0)
// B ks0 frags (2 reads)
#define READ_B0(DST, BUF)                                                      \
    do {                                                                       \
        DST[0] = *(const bf16x8*)(pB[0] + (BUF));                              \
        DST[1] = *(const bf16x8*)(pB[0] + (BUF) + 2048);                       \
    } while (0)
// B ks1..3 frags (6 reads)
#define READ_B123(BUF)                                                         \
    do {                                                                       \
        bfk[0][0] = *(const bf16x8*)(pB[1] + (BUF));                           \
        bfk[0][1] = *(const bf16x8*)(pB[1] + (BUF) + 2048);                    \
        bfk[1][0] = *(const bf16x8*)(pB[2] + (BUF));                           \
        bfk[1][1] = *(const bf16x8*)(pB[2] + (BUF) + 2048);                    \
        bfk[2][0] = *(const bf16x8*)(pB[3] + (BUF));                           \
        bfk[2][1] = *(const bf16x8*)(pB[3] + (BUF) + 2048);                    \
    } while (0)

    // prologue: stage B0,A0,B1 (12 loads); drain to 4 (B1 in flight); barrier;
    // first-tile ks0 frag reads (one-time exposed burst).
    stageB(0, 0); stageB(0, 1); stageA(0, 0); stageA(0, 1); stageB(1, 0); stageB(1, 1);
    asm volatile("s_waitcnt vmcnt(4)" ::: "memory");
    __builtin_amdgcn_s_barrier();
    asm volatile("" ::: "memory");
    READ_B0(bf0a, 0);
    READ_A(afA, 0, 0);

#define TILE(T, BUF, NBUF, BF0C, BF0N)                                         \
    do {                                                                       \
        const int t = (T);                                                     \
        /* ph0 */                                                              \
        READ_B123(BUF);                                                        \
        READ_A(afB, BUF, 1);                                                   \
        stageA(t + 1, 0);                                                      \
        MFMA_KS(afA, BF0C[0], BF0C[1]);                                        \
        /* ph1 */                                                              \
        READ_A(afA, BUF, 2);                                                   \
        stageA(t + 1, 1);                                                      \
        MFMA_KS(afB, bfk[0][0], bfk[0][1]);                                    \
        asm volatile("s_waitcnt lgkmcnt(4)" ::: "memory"); /* B reads older */ \
        __builtin_amdgcn_sched_barrier(0);                 /* -> retired     */ \
        __builtin_amdgcn_s_barrier();       /* mid: B-slot(t) free */          \
        asm volatile("" ::: "memory");                                         \
        /* ph2 */                                                              \
        READ_A(afB, BUF, 3);                                                   \
        stageB(t + 2, 0);                                                      \
        MFMA_KS(afA, bfk[1][0], bfk[1][1]);                                    \
        /* ph3 */                                                              \
        stageB(t + 2, 1);                                                      \
        asm volatile("s_waitcnt vmcnt(4) lgkmcnt(0)" ::: "memory");            \
        __builtin_amdgcn_s_barrier();       /* tile: buf(t+1) ready */         \
        asm volatile("" ::: "memory");                                         \
        if (t < 63) { READ_B0(BF0N, NBUF); READ_A(afA, NBUF, 0); }             \
        __builtin_amdgcn_sched_barrier(0);                                     \
        MFMA_KS(afB, bfk[2][0], bfk[2][1]);                                    \
    } while (0)

#pragma unroll 1
    for (int tt = 0; tt < 64; tt += 2) {
        TILE(tt,     0,     16384, bf0a, bf0b);
        TILE(tt + 1, 16384, 0,     bf0b, bf0a);
    }
#undef TILE
#undef MFMA_KS
#undef READ_A
#undef READ_B0
#undef READ_B123

    // epilogue: C/D 32x32 layout col=lane&31, row=(reg&3)+8*(reg>>2)+4*hi
    const int ccol = n0 + wn * 64 + r32;
    const int crow = m0 + wm * 128 + 4 * hi;
#pragma unroll
    for (int mi = 0; mi < 4; ++mi)
#pragma unroll
        for (int nj = 0; nj < 2; ++nj)
#pragma unroll
            for (int reg = 0; reg < 16; ++reg) {
                const int row = crow + mi * 32 + (reg & 3) + 8 * (reg >> 2);
                C[(size_t)row * N_DIM + ccol + nj * 32] = acc[mi][nj][reg];
            }
}

// ---- emergency fallback (only if ws too small) ------------------------------
__global__ void naive_kernel(const float* __restrict__ x, const int* __restrict__ packed,
                             const float* __restrict__ params, float* __restrict__ out) {
    int idx = blockIdx.x * blockDim.x + threadIdx.x;
    if (idx >= M_DIM * N_DIM) return;
    int m = idx / N_DIM, o = idx % N_DIM;
    const float* xr = x + (size_t)m * K_DIM;
    float sum = 0.f;
    for (int gi = 0; gi < K_DIM / 256; ++gi) {
        int g = o * (K_DIM / 256) + gi;
        float s = params[2 * g], z = params[2 * g + 1];
        const int* p = packed + (size_t)g * 128;
        const float* xx = xr + gi * 256;
        for (int j = 0; j < 128; ++j) {
            int v = p[j];
            sum += xx[2 * j]     * ((float)(v & 15) * s + z);
            sum += xx[2 * j + 1] * ((float)((v >> 4) & 15) * s + z);
        }
    }
    out[idx] = sum;
}

extern "C" void kernel_launch(void* const* d_in, const int* in_sizes, int n_in,
                              void* d_out, int out_size, void* d_ws, size_t ws_size,
                              hipStream_t stream) {
    const float* x      = (const float*)d_in[0];
    const int*   packed = (const int*)d_in[1];
    const float* params = (const float*)d_in[2];
    float* out = (float*)d_out;

    const size_t a_bytes = (size_t)M_DIM * K_DIM * 2;   // 67.1 MB bf16 x
    const size_t w_bytes = (size_t)N_DIM * K_DIM * 2;   // 33.6 MB bf16 W

    if (ws_size >= a_bytes + w_bytes) {
        ushort* Abf = (ushort*)d_ws;
        ushort* Wbf = (ushort*)((char*)d_ws + a_bytes);

        prep_kernel<<<24576, 256, 0, stream>>>(x, packed, params, Abf, Wbf);

        // 32 M-tiles x 16 N-tiles = 512 blocks, XCD-swizzled inside kernel
        gemm_bt<<<512, 512, 0, stream>>>(Abf, Wbf, out);
    } else {
        int n = M_DIM * N_DIM;
        naive_kernel<<<(n + 255) / 256, 256, 0, stream>>>(x, packed, params, out);
    }
}